// Round 5
// baseline (387.540 us; speedup 1.0000x reference)
//
#include <hip/hip_runtime.h>
#include <hip/hip_bf16.h>
#include <stdint.h>

// ---------------------------------------------------------------------------
// SGI grid-GCN head on MI355X.  Round 5:
//  - gemm_ho: h-GEMM and origin-GEMM merged (block-uniform branch on y);
//    identity-add now via LDS-staged xt tile (global_load_lds 16B) instead of
//    64 scalar 2B global reads per lane (the r4 regression).
//  - gemm2 split-K x2 (grid 32x4x8) -> 4 blocks/CU; stencil2 sums partials.
//  - runtime ws_size check: merged path needs ~192MB, falls back to split
//    launches with aliased buffers otherwise.
//  4-5 dispatches: prep, gemm_ho[, gemm_o], gemm2k, stencil2.
// ---------------------------------------------------------------------------

typedef __bf16 bf16;
typedef float f32x4 __attribute__((ext_vector_type(4)));
typedef bf16 bf16x8 __attribute__((ext_vector_type(8)));

#define NB 4
#define NN 4096
#define CIN 1536
#define HIDF 1536
#define OUTF 512
#define YH (HIDF / 128)  // 12 h-tiles in y

__device__ __forceinline__ float degree_of(int n) {
  const int x = n & 63, y = n >> 6;
  return 1.0f + (x > 0) + (x < 63) + (y > 0) + (y < 63);
}
__device__ __forceinline__ float deg2(int gx, int gy) {
  return 1.0f + (gx > 0) + (gx < 63) + (gy > 0) + (gy < 63);
}

// ------------------------------- prep (unchanged from r4) -------------------
#define XBLK 6144
#define W1BLK 576
#define W2BLK 192

__global__ __launch_bounds__(256) void prep(
    const float* __restrict__ x, const float* __restrict__ W1,
    const float* __restrict__ W2, const float* __restrict__ Wl,
    bf16* __restrict__ xt, bf16* __restrict__ xa, bf16* __restrict__ w1t,
    bf16* __restrict__ w2t, bf16* __restrict__ wlt) {
  __shared__ float vt[64 * 64];
  __shared__ float at[64 * 64];
  const int B = blockIdx.x, t = threadIdx.x;
  const int tx = t & 15, ty = t >> 4;
  const int lane = t & 63, w = t >> 6;
  const int u = lane & 7, n3 = lane >> 3;

  if (B < XBLK) {
    const int slot = B >> 3;
    const int nt = (B & 7) * 8 + (slot & 7);
    const int ct = (slot >> 3) % 24;
    const int bb = (slot >> 3) / 24;
    const int gy = nt;
    const int n0 = nt * 64, c0 = ct * 64;
    const float* xb = x + (long)bb * CIN * NN;
#pragma unroll
    for (int cc = 0; cc < 4; cc++) {
      const int cl = ty * 4 + cc;
      const float* row = xb + (long)(c0 + cl) * NN + n0;
      const int nb = tx * 4;
      f32x4 v = *(const f32x4*)(row + nb);
      f32x4 up = {0.f, 0.f, 0.f, 0.f};
      f32x4 dn = {0.f, 0.f, 0.f, 0.f};
      if (gy > 0) up = *(const f32x4*)(row + nb - 64);
      if (gy < 63) dn = *(const f32x4*)(row + nb + 64);
      const float lf = (tx > 0) ? row[nb - 1] : 0.f;
      const float rt = (tx < 15) ? row[nb + 4] : 0.f;
      f32x4 a;
#pragma unroll
      for (int i = 0; i < 4; i++) {
        const int gx = nb + i;
        const float degn = deg2(gx, gy);
        float s = v[i] * (1.0f / degn);
        const float lv = (i == 0) ? lf : v[i - 1];
        const float rv = (i == 3) ? rt : v[i + 1];
        if (gx > 0) s += lv * rsqrtf(degn * deg2(gx - 1, gy));
        if (gx < 63) s += rv * rsqrtf(degn * deg2(gx + 1, gy));
        if (gy > 0) s += up[i] * rsqrtf(degn * deg2(gx, gy - 1));
        if (gy < 63) s += dn[i] * rsqrtf(degn * deg2(gx, gy + 1));
        a[i] = s;
      }
      const int chunk = tx ^ (2 * ((cl >> 3) & 7));
      *(f32x4*)&vt[cl * 64 + chunk * 4] = v;
      *(f32x4*)&at[cl * 64 + chunk * 4] = a;
    }
    __syncthreads();
    bf16* xtb = xt + (long)bb * NN * CIN;
    bf16* xab = xa + (long)bb * NN * CIN;
#pragma unroll
    for (int q = 0; q < 4; q++) {
      const int j = q * 4 + w;
      const int arr = j & 1, r = j >> 1;
      const int nl = n3 + 8 * r;
      const float* s = arr ? at : vt;
      bf16x8 o;
#pragma unroll
      for (int jj = 0; jj < 8; jj++) {
        const int cl = u * 8 + jj;
        const int col = nl ^ (8 * ((cl >> 3) & 7));
        o[jj] = (bf16)s[cl * 64 + col];
      }
      bf16* outp = arr ? xab : xtb;
      *(bf16x8*)&outp[(long)(n0 + nl) * CIN + c0 + u * 8] = o;
    }
  } else {
    int B2 = B - XBLK;
    const float* srcp;
    bf16* dstp;
    int Fdim, Kd, nt, ct;
    if (B2 < W1BLK) {
      nt = B2 / 24; ct = B2 % 24; srcp = W1; dstp = w1t; Fdim = HIDF; Kd = CIN;
    } else if (B2 < W1BLK + W2BLK) {
      const int l = B2 - W1BLK;
      nt = l / 24; ct = l % 24; srcp = W2; dstp = w2t; Fdim = OUTF; Kd = HIDF;
    } else {
      const int l = B2 - W1BLK - W2BLK;
      nt = l / 24; ct = l % 24; srcp = Wl; dstp = wlt; Fdim = OUTF; Kd = CIN;
    }
    const int n0 = nt * 64, c0 = ct * 64;
#pragma unroll
    for (int cc = 0; cc < 4; cc++) {
      const int cl = ty * 4 + cc;
      const float* row = srcp + (long)(c0 + cl) * Fdim + n0;
      f32x4 v = *(const f32x4*)(row + tx * 4);
      const int chunk = tx ^ (2 * ((cl >> 3) & 7));
      *(f32x4*)&vt[cl * 64 + chunk * 4] = v;
    }
    __syncthreads();
#pragma unroll
    for (int q = 0; q < 2; q++) {
      const int r = q * 4 + w;
      const int nl = n3 + 8 * r;
      bf16x8 o;
#pragma unroll
      for (int jj = 0; jj < 8; jj++) {
        const int cl = u * 8 + jj;
        const int col = nl ^ (8 * ((cl >> 3) & 7));
        o[jj] = (bf16)vt[cl * 64 + col];
      }
      *(bf16x8*)&dstp[(long)(n0 + nl) * Kd + c0 + u * 8] = o;
    }
  }
}

// ------------------------------- GEMM core ---------------------------------
__device__ __forceinline__ void async_copy16(const void* g, void* l) {
  __builtin_amdgcn_global_load_lds(
      (const __attribute__((address_space(1))) void*)g,
      (__attribute__((address_space(3))) void*)l, 16, 0, 0);
}

struct GemmCtx {
  f32x4 acc[4][4];
  int wave, lane, wm, wn, quad, l15;
};

__device__ __forceinline__ void gemm_init(GemmCtx& cx, int t) {
  cx.wave = t >> 6;
  cx.lane = t & 63;
  cx.wm = (cx.wave & 1) * 64;
  cx.wn = (cx.wave >> 1) * 64;
  cx.quad = cx.lane >> 4;
  cx.l15 = cx.lane & 15;
#pragma unroll
  for (int i = 0; i < 4; i++)
#pragma unroll
    for (int j = 0; j < 4; j++) cx.acc[i][j] = {0.f, 0.f, 0.f, 0.f};
}

// K-loop over [k0,k1); row stride LDK (all our GEMMs have LDK=1536).
template <int LDK>
__device__ __forceinline__ void gemm_kloop(GemmCtx& cx, const bf16* Ab,
                                           const bf16* Bb, bf16* As, bf16* Bs,
                                           int k0, int k1) {
  const int r = cx.lane >> 3, c8 = cx.lane & 7;
  const int fchunk = c8 ^ r;
  for (int kt = k0; kt < k1; kt += 64) {
#pragma unroll
    for (int i = 0; i < 4; i++) {
      const int row = i * 32 + cx.wave * 8;
      async_copy16(Ab + (long)(row + r) * LDK + kt + fchunk * 8, &As[row * 64]);
      async_copy16(Bb + (long)(row + r) * LDK + kt + fchunk * 8, &Bs[row * 64]);
    }
    __syncthreads();
#pragma unroll
    for (int kk = 0; kk < 2; kk++) {
      const int q = kk * 4 + cx.quad;
      bf16x8 af[4], bfv[4];
#pragma unroll
      for (int mr = 0; mr < 4; mr++) {
        const int m = cx.wm + mr * 16 + cx.l15;
        af[mr] = *(const bf16x8*)&As[m * 64 + (q ^ (m & 7)) * 8];
      }
#pragma unroll
      for (int nc = 0; nc < 4; nc++) {
        const int n = cx.wn + nc * 16 + cx.l15;
        bfv[nc] = *(const bf16x8*)&Bs[n * 64 + (q ^ (n & 7)) * 8];
      }
#pragma unroll
      for (int mr = 0; mr < 4; mr++)
#pragma unroll
        for (int nc = 0; nc < 4; nc++)
          cx.acc[mr][nc] = __builtin_amdgcn_mfma_f32_16x16x32_bf16(
              af[mr], bfv[nc], cx.acc[mr][nc], 0, 0, 0);
    }
    __syncthreads();
  }
}

// Merged h|origin GEMM.  yb = blockIdx.y + y_off:
//   yb <  12 : h = bf16(relu(xa@W1+b1) + xt)   (xt tile LDS-staged)
//   yb >= 12 : origin = xt@Wl + bl             (fp32)
__global__ __launch_bounds__(256) void gemm_ho(
    const bf16* __restrict__ xa, const bf16* __restrict__ xt,
    const bf16* __restrict__ w1t, const bf16* __restrict__ wlt,
    bf16* __restrict__ h, float* __restrict__ orig,
    const float* __restrict__ b1, const float* __restrict__ bl, int y_off) {
  __shared__ bf16 S[2 * 128 * 64];
  bf16* As = S;
  bf16* Bs = S + 128 * 64;
  GemmCtx cx;
  gemm_init(cx, threadIdx.x);
  const int yb = blockIdx.y + y_off;
  const int m0 = blockIdx.x * 128, z = blockIdx.z;
  const bool is_h = yb < YH;
  const int n0 = (is_h ? yb : yb - YH) * 128;
  const bf16* A = (is_h ? xa : xt) + (long)z * NN * CIN + (long)m0 * CIN;
  const bf16* Bw = (is_h ? w1t : wlt) + (long)n0 * CIN;
  gemm_kloop<CIN>(cx, A, Bw, As, Bs, 0, CIN);

  if (is_h) {
    // stage xt[m0:m0+128][n0:n0+128] into S (32KB) via global_load_lds 16B
    const bf16* Xb = xt + (long)z * NN * CIN;
    bf16* Xs = S;
    const int lane = cx.lane, wave = cx.wave;
#pragma unroll
    for (int i = 0; i < 8; i++) {
      const int rb = i * 16 + wave * 4;  // wave-uniform row base
      async_copy16(
          Xb + (long)(m0 + rb + (lane >> 4)) * CIN + n0 + (lane & 15) * 8,
          &Xs[rb * 128]);
    }
    __syncthreads();
    bf16* Cb = h + (long)z * NN * HIDF;
#pragma unroll
    for (int mr = 0; mr < 4; mr++)
#pragma unroll
      for (int nc = 0; nc < 4; nc++) {
        const int gnl = cx.wn + nc * 16 + cx.l15;
        const float bv = b1[n0 + gnl];
#pragma unroll
        for (int j = 0; j < 4; j++) {
          const int gml = cx.wm + mr * 16 + cx.quad * 4 + j;
          float v = cx.acc[mr][nc][j] + bv;
          v = v > 0.f ? v : 0.f;
          v += (float)Xs[gml * 128 + gnl];
          Cb[(long)(m0 + gml) * HIDF + n0 + gnl] = (bf16)v;
        }
      }
  } else {
    float* Cb = orig + (long)z * NN * OUTF;
#pragma unroll
    for (int mr = 0; mr < 4; mr++)
#pragma unroll
      for (int nc = 0; nc < 4; nc++) {
        const int gn = n0 + cx.wn + nc * 16 + cx.l15;
        const float bv = bl[gn];
#pragma unroll
        for (int j = 0; j < 4; j++) {
          const int gm = m0 + cx.wm + mr * 16 + cx.quad * 4 + j;
          Cb[(long)gm * OUTF + gn] = cx.acc[mr][nc][j] + bv;
        }
      }
  }
}

// gemm2 with optional split-K: z = batch | part<<2; part p covers
// [p*CIN/nparts, (p+1)*CIN/nparts), writes g2a (p=0) or g2b (p=1).
__global__ __launch_bounds__(256) void gemm2k(
    const bf16* __restrict__ hb, const bf16* __restrict__ w2t,
    float* __restrict__ g2a, float* __restrict__ g2b, int kspan) {
  __shared__ bf16 S[2 * 128 * 64];
  GemmCtx cx;
  gemm_init(cx, threadIdx.x);
  const int m0 = blockIdx.x * 128, n0 = blockIdx.y * 128;
  const int z = blockIdx.z & 3, part = blockIdx.z >> 2;
  const int k0 = part * kspan;
  gemm_kloop<HIDF>(cx, hb + (long)z * NN * HIDF + (long)m0 * HIDF,
                   w2t + (long)n0 * HIDF, S, S + 128 * 64, k0, k0 + kspan);
  float* Cb = (part ? g2b : g2a) + (long)z * NN * OUTF;
#pragma unroll
  for (int mr = 0; mr < 4; mr++)
#pragma unroll
    for (int nc = 0; nc < 4; nc++) {
      const int gn = n0 + cx.wn + nc * 16 + cx.l15;
#pragma unroll
      for (int j = 0; j < 4; j++) {
        const int gm = m0 + cx.wm + mr * 16 + cx.quad * 4 + j;
        Cb[(long)gm * OUTF + gn] = cx.acc[mr][nc][j];
      }
    }
}

// ------------------------------- stencil2 ----------------------------------
// out[b][f][n] = (Agg(g2a[+g2b])[n][f] + b2[f]) * Origin[n][f]; LDS transpose.
__global__ __launch_bounds__(256) void stencil2(
    const float* __restrict__ g2a, const float* __restrict__ g2b,
    const float* __restrict__ Orig, const float* __restrict__ b2,
    float* __restrict__ out, int two) {
  __shared__ float tile[16][513];
  const int blk = blockIdx.x;
  const int s = ((blk & 7) << 5) + (blk >> 3);  // XCD-contiguous strips
  const int n0 = s * 16, b = blockIdx.y;
  const int t = threadIdx.x;
  const int fq = t & 127, nl = t >> 7;
  const int f = fq * 4;
  const f32x4 bv = *(const f32x4*)(b2 + f);
#pragma unroll
  for (int p = 0; p < 8; p++) {
    const int nLoc = p * 2 + nl;
    const int n = n0 + nLoc;
    const int gx = n & 63, gy = n >> 6;
    const float degn = degree_of(n);
    const float ws = 1.0f / degn;
    const float wL = (gx > 0) ? rsqrtf(degn * degree_of(n - 1)) : 0.f;
    const float wR = (gx < 63) ? rsqrtf(degn * degree_of(n + 1)) : 0.f;
    const float wU = (gy > 0) ? rsqrtf(degn * degree_of(n - 64)) : 0.f;
    const float wD = (gy < 63) ? rsqrtf(degn * degree_of(n + 64)) : 0.f;
    const long rb = ((long)b * NN + n) * (long)OUTF + f;
    f32x4 a = {0.f, 0.f, 0.f, 0.f};
    for (int q = 0; q <= two; q++) {
      const float* G = q ? g2b : g2a;
      f32x4 g = *(const f32x4*)(G + rb);
#pragma unroll
      for (int i = 0; i < 4; i++) a[i] += g[i] * ws;
      if (gx > 0) {
        f32x4 u = *(const f32x4*)(G + rb - OUTF);
#pragma unroll
        for (int i = 0; i < 4; i++) a[i] += u[i] * wL;
      }
      if (gx < 63) {
        f32x4 u = *(const f32x4*)(G + rb + OUTF);
#pragma unroll
        for (int i = 0; i < 4; i++) a[i] += u[i] * wR;
      }
      if (gy > 0) {
        f32x4 u = *(const f32x4*)(G + rb - 64L * OUTF);
#pragma unroll
        for (int i = 0; i < 4; i++) a[i] += u[i] * wU;
      }
      if (gy < 63) {
        f32x4 u = *(const f32x4*)(G + rb + 64L * OUTF);
#pragma unroll
        for (int i = 0; i < 4; i++) a[i] += u[i] * wD;
      }
    }
    f32x4 og = *(const f32x4*)(Orig + rb);
#pragma unroll
    for (int i = 0; i < 4; i++) tile[nLoc][f + i] = (a[i] + bv[i]) * og[i];
  }
  __syncthreads();
  const int nl2 = t & 15, f0 = t >> 4;
#pragma unroll
  for (int q = 0; q < 32; q++) {
    const int ff = q * 16 + f0;
    out[((long)b * OUTF + ff) * (long)NN + n0 + nl2] = tile[nl2][ff];
  }
}

// ------------------------------- launcher ----------------------------------
extern "C" void kernel_launch(void* const* d_in, const int* in_sizes, int n_in,
                              void* d_out, int out_size, void* d_ws,
                              size_t ws_size, hipStream_t stream) {
  const float* x = (const float*)d_in[0];
  const float* W1 = (const float*)d_in[1];
  const float* b1 = (const float*)d_in[2];
  const float* W2 = (const float*)d_in[3];
  const float* b2 = (const float*)d_in[4];
  const float* Wl = (const float*)d_in[5];
  const float* bl = (const float*)d_in[6];
  float* out = (float*)d_out;

  uint8_t* ws = (uint8_t*)d_ws;
  size_t off = 0;
  auto alloc = [&](size_t bytes) -> void* {
    void* p = ws + off;
    off += (bytes + 255) & ~(size_t)255;
    return p;
  };
  bf16* xt = (bf16*)alloc((size_t)NB * NN * CIN * 2);   // 50.3 MB
  bf16* xa = (bf16*)alloc((size_t)NB * NN * CIN * 2);   // 50.3 MB
  bf16* hb = (bf16*)alloc((size_t)NB * NN * HIDF * 2);  // 50.3 MB
  bf16* w1t = (bf16*)alloc((size_t)HIDF * CIN * 2);     // 4.7 MB
  bf16* w2t = (bf16*)alloc((size_t)OUTF * HIDF * 2);    // 1.6 MB
  bf16* wlt = (bf16*)alloc((size_t)OUTF * CIN * 2);     // 1.6 MB
  const size_t obytes = (size_t)NB * NN * OUTF * 4;     // 33.5 MB
  const bool merged = (ws_size >= off + obytes);
  float* origin = merged ? (float*)alloc(obytes) : (float*)xa;
  float* g2a = merged ? (float*)xa : (float*)xt;  // dead slots by then
  float* g2b = (float*)xt;                        // merged path only

  prep<<<XBLK + W1BLK + 2 * W2BLK, 256, 0, stream>>>(x, W1, W2, Wl, xt, xa,
                                                     w1t, w2t, wlt);
  if (merged) {
    // h and origin in one launch (origin buffer is distinct from xa)
    gemm_ho<<<dim3(NN / 128, YH + OUTF / 128, NB), 256, 0, stream>>>(
        xa, xt, w1t, wlt, hb, origin, b1, bl, 0);
    // g2 split-K x2 -> g2a (aliases xa), g2b (aliases xt)
    gemm2k<<<dim3(NN / 128, OUTF / 128, NB * 2), 256, 0, stream>>>(
        hb, w2t, g2a, g2b, CIN / 2);
    stencil2<<<dim3(256, NB), 256, 0, stream>>>(g2a, g2b, origin, b2, out, 1);
  } else {
    // fallback: split launches, origin aliases xa (dead after h pass)
    gemm_ho<<<dim3(NN / 128, YH, NB), 256, 0, stream>>>(xa, xt, w1t, wlt, hb,
                                                        origin, b1, bl, 0);
    gemm_ho<<<dim3(NN / 128, OUTF / 128, NB), 256, 0, stream>>>(
        xa, xt, w1t, wlt, hb, origin, b1, bl, YH);
    gemm2k<<<dim3(NN / 128, OUTF / 128, NB), 256, 0, stream>>>(hb, w2t, g2a,
                                                               g2a, CIN);
    stencil2<<<dim3(256, NB), 256, 0, stream>>>(g2a, g2a, origin, b2, out, 0);
  }
}

// Round 6
// 381.792 us; speedup vs baseline: 1.0151x; 1.0151x over previous
//
#include <hip/hip_runtime.h>
#include <hip/hip_bf16.h>
#include <stdint.h>

// ---------------------------------------------------------------------------
// SGI grid-GCN head on MI355X.  Round 6:
//  - r4 structure restored (prep, gemm_h, gemm_o, gemm2, stencil2; 159 MB).
//  - gemm_h identity-add: xt tile staged via VGPR->ds_write_b128 with row
//    stride 132 bf16 (quad stride 264 dwords = 8 mod 32 -> each quad gets its
//    own bank octet; r5's packed global_load_lds staging was 4-way conflicted,
//    786K SQ_LDS_BANK_CONFLICT).
//  - split-K gemm2 and dual-partial stencil2 reverted (r5 regression).
// ---------------------------------------------------------------------------

typedef __bf16 bf16;
typedef float f32x4 __attribute__((ext_vector_type(4)));
typedef bf16 bf16x8 __attribute__((ext_vector_type(8)));

#define NB 4
#define NN 4096
#define CIN 1536
#define HIDF 1536
#define OUTF 512
#define XSTRIDE 132   // padded LDS row stride for the xt epilogue tile

__device__ __forceinline__ float degree_of(int n) {
  const int x = n & 63, y = n >> 6;
  return 1.0f + (x > 0) + (x < 63) + (y > 0) + (y < 63);
}
__device__ __forceinline__ float deg2(int gx, int gy) {
  return 1.0f + (gx > 0) + (gx < 63) + (gy > 0) + (gy < 63);
}

// ------------------------------- prep (r4) ----------------------------------
#define XBLK 6144
#define W1BLK 576
#define W2BLK 192

__global__ __launch_bounds__(256) void prep(
    const float* __restrict__ x, const float* __restrict__ W1,
    const float* __restrict__ W2, const float* __restrict__ Wl,
    bf16* __restrict__ xt, bf16* __restrict__ xa, bf16* __restrict__ w1t,
    bf16* __restrict__ w2t, bf16* __restrict__ wlt) {
  __shared__ float vt[64 * 64];
  __shared__ float at[64 * 64];
  const int B = blockIdx.x, t = threadIdx.x;
  const int tx = t & 15, ty = t >> 4;
  const int lane = t & 63, w = t >> 6;
  const int u = lane & 7, n3 = lane >> 3;

  if (B < XBLK) {
    const int slot = B >> 3;
    const int nt = (B & 7) * 8 + (slot & 7);
    const int ct = (slot >> 3) % 24;
    const int bb = (slot >> 3) / 24;
    const int gy = nt;
    const int n0 = nt * 64, c0 = ct * 64;
    const float* xb = x + (long)bb * CIN * NN;
#pragma unroll
    for (int cc = 0; cc < 4; cc++) {
      const int cl = ty * 4 + cc;
      const float* row = xb + (long)(c0 + cl) * NN + n0;
      const int nb = tx * 4;
      f32x4 v = *(const f32x4*)(row + nb);
      f32x4 up = {0.f, 0.f, 0.f, 0.f};
      f32x4 dn = {0.f, 0.f, 0.f, 0.f};
      if (gy > 0) up = *(const f32x4*)(row + nb - 64);
      if (gy < 63) dn = *(const f32x4*)(row + nb + 64);
      const float lf = (tx > 0) ? row[nb - 1] : 0.f;
      const float rt = (tx < 15) ? row[nb + 4] : 0.f;
      f32x4 a;
#pragma unroll
      for (int i = 0; i < 4; i++) {
        const int gx = nb + i;
        const float degn = deg2(gx, gy);
        float s = v[i] * (1.0f / degn);
        const float lv = (i == 0) ? lf : v[i - 1];
        const float rv = (i == 3) ? rt : v[i + 1];
        if (gx > 0) s += lv * rsqrtf(degn * deg2(gx - 1, gy));
        if (gx < 63) s += rv * rsqrtf(degn * deg2(gx + 1, gy));
        if (gy > 0) s += up[i] * rsqrtf(degn * deg2(gx, gy - 1));
        if (gy < 63) s += dn[i] * rsqrtf(degn * deg2(gx, gy + 1));
        a[i] = s;
      }
      const int chunk = tx ^ (2 * ((cl >> 3) & 7));
      *(f32x4*)&vt[cl * 64 + chunk * 4] = v;
      *(f32x4*)&at[cl * 64 + chunk * 4] = a;
    }
    __syncthreads();
    bf16* xtb = xt + (long)bb * NN * CIN;
    bf16* xab = xa + (long)bb * NN * CIN;
#pragma unroll
    for (int q = 0; q < 4; q++) {
      const int j = q * 4 + w;
      const int arr = j & 1, r = j >> 1;
      const int nl = n3 + 8 * r;
      const float* s = arr ? at : vt;
      bf16x8 o;
#pragma unroll
      for (int jj = 0; jj < 8; jj++) {
        const int cl = u * 8 + jj;
        const int col = nl ^ (8 * ((cl >> 3) & 7));
        o[jj] = (bf16)s[cl * 64 + col];
      }
      bf16* outp = arr ? xab : xtb;
      *(bf16x8*)&outp[(long)(n0 + nl) * CIN + c0 + u * 8] = o;
    }
  } else {
    int B2 = B - XBLK;
    const float* srcp;
    bf16* dstp;
    int Fdim, Kd, nt, ct;
    if (B2 < W1BLK) {
      nt = B2 / 24; ct = B2 % 24; srcp = W1; dstp = w1t; Fdim = HIDF; Kd = CIN;
    } else if (B2 < W1BLK + W2BLK) {
      const int l = B2 - W1BLK;
      nt = l / 24; ct = l % 24; srcp = W2; dstp = w2t; Fdim = OUTF; Kd = HIDF;
    } else {
      const int l = B2 - W1BLK - W2BLK;
      nt = l / 24; ct = l % 24; srcp = Wl; dstp = wlt; Fdim = OUTF; Kd = CIN;
    }
    const int n0 = nt * 64, c0 = ct * 64;
#pragma unroll
    for (int cc = 0; cc < 4; cc++) {
      const int cl = ty * 4 + cc;
      const float* row = srcp + (long)(c0 + cl) * Fdim + n0;
      f32x4 v = *(const f32x4*)(row + tx * 4);
      const int chunk = tx ^ (2 * ((cl >> 3) & 7));
      *(f32x4*)&vt[cl * 64 + chunk * 4] = v;
    }
    __syncthreads();
#pragma unroll
    for (int q = 0; q < 2; q++) {
      const int r = q * 4 + w;
      const int nl = n3 + 8 * r;
      bf16x8 o;
#pragma unroll
      for (int jj = 0; jj < 8; jj++) {
        const int cl = u * 8 + jj;
        const int col = nl ^ (8 * ((cl >> 3) & 7));
        o[jj] = (bf16)vt[cl * 64 + col];
      }
      *(bf16x8*)&dstp[(long)(n0 + nl) * Kd + c0 + u * 8] = o;
    }
  }
}

// ------------------------------- GEMM core ---------------------------------
__device__ __forceinline__ void async_copy16(const void* g, void* l) {
  __builtin_amdgcn_global_load_lds(
      (const __attribute__((address_space(1))) void*)g,
      (__attribute__((address_space(3))) void*)l, 16, 0, 0);
}

struct GemmCtx {
  f32x4 acc[4][4];
  int wave, lane, wm, wn, quad, l15;
};

__device__ __forceinline__ void gemm_init(GemmCtx& cx, int t) {
  cx.wave = t >> 6;
  cx.lane = t & 63;
  cx.wm = (cx.wave & 1) * 64;
  cx.wn = (cx.wave >> 1) * 64;
  cx.quad = cx.lane >> 4;
  cx.l15 = cx.lane & 15;
#pragma unroll
  for (int i = 0; i < 4; i++)
#pragma unroll
    for (int j = 0; j < 4; j++) cx.acc[i][j] = {0.f, 0.f, 0.f, 0.f};
}

template <int K>
__device__ __forceinline__ void gemm_kloop(GemmCtx& cx, const bf16* Ab,
                                           const bf16* Bb, bf16* As,
                                           bf16* Bs) {
  const int r = cx.lane >> 3, c8 = cx.lane & 7;
  const int fchunk = c8 ^ r;
  for (int kt = 0; kt < K; kt += 64) {
#pragma unroll
    for (int i = 0; i < 4; i++) {
      const int row = i * 32 + cx.wave * 8;
      async_copy16(Ab + (long)(row + r) * K + kt + fchunk * 8, &As[row * 64]);
      async_copy16(Bb + (long)(row + r) * K + kt + fchunk * 8, &Bs[row * 64]);
    }
    __syncthreads();
#pragma unroll
    for (int kk = 0; kk < 2; kk++) {
      const int q = kk * 4 + cx.quad;
      bf16x8 af[4], bfv[4];
#pragma unroll
      for (int mr = 0; mr < 4; mr++) {
        const int m = cx.wm + mr * 16 + cx.l15;
        af[mr] = *(const bf16x8*)&As[m * 64 + (q ^ (m & 7)) * 8];
      }
#pragma unroll
      for (int nc = 0; nc < 4; nc++) {
        const int n = cx.wn + nc * 16 + cx.l15;
        bfv[nc] = *(const bf16x8*)&Bs[n * 64 + (q ^ (n & 7)) * 8];
      }
#pragma unroll
      for (int mr = 0; mr < 4; mr++)
#pragma unroll
        for (int nc = 0; nc < 4; nc++)
          cx.acc[mr][nc] = __builtin_amdgcn_mfma_f32_16x16x32_bf16(
              af[mr], bfv[nc], cx.acc[mr][nc], 0, 0, 0);
    }
    __syncthreads();
  }
}

// h = bf16( relu(xa @ w1t^T + b1) + xt )   [B][NN][HIDF]
// xt tile staged into LDS with padded stride (conflict-free epilogue reads).
__global__ __launch_bounds__(256) void gemm_h(
    const bf16* __restrict__ xa, const bf16* __restrict__ w1t,
    const bf16* __restrict__ xt, bf16* __restrict__ h,
    const float* __restrict__ b1) {
  __shared__ bf16 S[128 * XSTRIDE];  // 33792 B >= 2*128*64*2 = 32768 B
  bf16* As = S;
  bf16* Bs = S + 128 * 64;
  GemmCtx cx;
  gemm_init(cx, threadIdx.x);
  const int m0 = blockIdx.x * 128, n0 = blockIdx.y * 128, z = blockIdx.z;
  gemm_kloop<CIN>(cx, xa + (long)z * NN * CIN + (long)m0 * CIN,
                  w1t + (long)n0 * CIN, As, Bs);

  // stage xt[m0:+128][n0:+128] -> S with row stride XSTRIDE (2 batches of 4)
  const bf16* Xb = xt + (long)z * NN * CIN;
  const int t = threadIdx.x;
  const int srow = t >> 4, scol = (t & 15) * 8;
#pragma unroll
  for (int half = 0; half < 2; half++) {
    bf16x8 v[4];
#pragma unroll
    for (int i = 0; i < 4; i++) {
      const int row = (half * 4 + i) * 16 + srow;
      v[i] = *(const bf16x8*)(Xb + (long)(m0 + row) * CIN + n0 + scol);
    }
#pragma unroll
    for (int i = 0; i < 4; i++) {
      const int row = (half * 4 + i) * 16 + srow;
      *(bf16x8*)&S[row * XSTRIDE + scol] = v[i];
    }
  }
  __syncthreads();

  bf16* Cb = h + (long)z * NN * HIDF;
#pragma unroll
  for (int mr = 0; mr < 4; mr++)
#pragma unroll
    for (int nc = 0; nc < 4; nc++) {
      const int gnl = cx.wn + nc * 16 + cx.l15;
      const float bv = b1[n0 + gnl];
#pragma unroll
      for (int j = 0; j < 4; j++) {
        const int gml = cx.wm + mr * 16 + cx.quad * 4 + j;
        float v = cx.acc[mr][nc][j] + bv;
        v = v > 0.f ? v : 0.f;
        v += (float)S[gml * XSTRIDE + gnl];
        Cb[(long)(m0 + gml) * HIDF + n0 + gnl] = (bf16)v;
      }
    }
}

// fp32-out GEMM (gemm_o with bias, gemm2 without).  K = 1536 both.
template <bool ADD_BIAS>
__global__ __launch_bounds__(256) void gemm_f32(
    const bf16* __restrict__ A, const bf16* __restrict__ Bw,
    float* __restrict__ C, const float* __restrict__ bias) {
  __shared__ bf16 As[128 * 64];
  __shared__ bf16 Bs[128 * 64];
  GemmCtx cx;
  gemm_init(cx, threadIdx.x);
  const int m0 = blockIdx.x * 128, n0 = blockIdx.y * 128, z = blockIdx.z;
  gemm_kloop<CIN>(cx, A + (long)z * NN * CIN + (long)m0 * CIN,
                  Bw + (long)n0 * CIN, As, Bs);
  float* Cb = C + (long)z * NN * OUTF;
#pragma unroll
  for (int mr = 0; mr < 4; mr++)
#pragma unroll
    for (int nc = 0; nc < 4; nc++) {
      const int gn = n0 + cx.wn + nc * 16 + cx.l15;
      float bv = 0.f;
      if (ADD_BIAS) bv = bias[gn];
#pragma unroll
      for (int j = 0; j < 4; j++) {
        const int gm = m0 + cx.wm + mr * 16 + cx.quad * 4 + j;
        Cb[(long)gm * OUTF + gn] = cx.acc[mr][nc][j] + bv;
      }
    }
}

// ------------------------------- stencil2 ----------------------------------
__global__ __launch_bounds__(256) void stencil2(
    const float* __restrict__ G2, const float* __restrict__ Orig,
    const float* __restrict__ b2, float* __restrict__ out) {
  __shared__ float tile[16][513];
  const int blk = blockIdx.x;
  const int s = ((blk & 7) << 5) + (blk >> 3);  // XCD-contiguous strips
  const int n0 = s * 16, b = blockIdx.y;
  const int t = threadIdx.x;
  const int fq = t & 127, nl = t >> 7;
  const int f = fq * 4;
  const f32x4 bv = *(const f32x4*)(b2 + f);
#pragma unroll
  for (int p = 0; p < 8; p++) {
    const int nLoc = p * 2 + nl;
    const int n = n0 + nLoc;
    const int gx = n & 63, gy = n >> 6;
    const float degn = degree_of(n);
    const float ws = 1.0f / degn;
    const long rb = ((long)b * NN + n) * (long)OUTF + f;
    f32x4 g = *(const f32x4*)(G2 + rb);
    f32x4 a;
#pragma unroll
    for (int i = 0; i < 4; i++) a[i] = g[i] * ws;
    if (gx > 0) {
      const float w = rsqrtf(degn * degree_of(n - 1));
      f32x4 u = *(const f32x4*)(G2 + rb - OUTF);
#pragma unroll
      for (int i = 0; i < 4; i++) a[i] += u[i] * w;
    }
    if (gx < 63) {
      const float w = rsqrtf(degn * degree_of(n + 1));
      f32x4 u = *(const f32x4*)(G2 + rb + OUTF);
#pragma unroll
      for (int i = 0; i < 4; i++) a[i] += u[i] * w;
    }
    if (gy > 0) {
      const float w = rsqrtf(degn * degree_of(n - 64));
      f32x4 u = *(const f32x4*)(G2 + rb - 64L * OUTF);
#pragma unroll
      for (int i = 0; i < 4; i++) a[i] += u[i] * w;
    }
    if (gy < 63) {
      const float w = rsqrtf(degn * degree_of(n + 64));
      f32x4 u = *(const f32x4*)(G2 + rb + 64L * OUTF);
#pragma unroll
      for (int i = 0; i < 4; i++) a[i] += u[i] * w;
    }
    f32x4 og = *(const f32x4*)(Orig + rb);
#pragma unroll
    for (int i = 0; i < 4; i++) tile[nLoc][f + i] = (a[i] + bv[i]) * og[i];
  }
  __syncthreads();
  const int nl2 = t & 15, f0 = t >> 4;
#pragma unroll
  for (int q = 0; q < 32; q++) {
    const int ff = q * 16 + f0;
    out[((long)b * OUTF + ff) * (long)NN + n0 + nl2] = tile[nl2][ff];
  }
}

// ------------------------------- launcher ----------------------------------
extern "C" void kernel_launch(void* const* d_in, const int* in_sizes, int n_in,
                              void* d_out, int out_size, void* d_ws,
                              size_t ws_size, hipStream_t stream) {
  const float* x = (const float*)d_in[0];
  const float* W1 = (const float*)d_in[1];
  const float* b1 = (const float*)d_in[2];
  const float* W2 = (const float*)d_in[3];
  const float* b2 = (const float*)d_in[4];
  const float* Wl = (const float*)d_in[5];
  const float* bl = (const float*)d_in[6];
  float* out = (float*)d_out;

  uint8_t* ws = (uint8_t*)d_ws;
  size_t off = 0;
  auto alloc = [&](size_t bytes) -> void* {
    void* p = ws + off;
    off += (bytes + 255) & ~(size_t)255;
    return p;
  };
  // Lifetimes: xt [prep..gemm_o], xa [prep..gemm_h], h [gemm_h..gemm2],
  //            origin [gemm_o..stencil2] (aliases xa), g2 [gemm2..stencil2]
  //            (aliases xt).  High-water ~159 MB.
  bf16* xt = (bf16*)alloc((size_t)NB * NN * CIN * 2);   // 50.3 MB
  bf16* xa = (bf16*)alloc((size_t)NB * NN * CIN * 2);   // 50.3 MB
  bf16* hb = (bf16*)alloc((size_t)NB * NN * HIDF * 2);  // 50.3 MB
  bf16* w1t = (bf16*)alloc((size_t)HIDF * CIN * 2);     // 4.7 MB
  bf16* w2t = (bf16*)alloc((size_t)OUTF * HIDF * 2);    // 1.6 MB
  bf16* wlt = (bf16*)alloc((size_t)OUTF * CIN * 2);     // 1.6 MB
  float* origin = (float*)xa;
  float* g2 = (float*)xt;

  prep<<<XBLK + W1BLK + 2 * W2BLK, 256, 0, stream>>>(x, W1, W2, Wl, xt, xa,
                                                     w1t, w2t, wlt);
  // h = relu(xa @ W1 + b1) + xt
  gemm_h<<<dim3(NN / 128, HIDF / 128, NB), 256, 0, stream>>>(xa, w1t, xt, hb,
                                                             b1);
  // origin = xt @ Wl + bl  (overwrites xa slot — xa dead after gemm_h)
  gemm_f32<true><<<dim3(NN / 128, OUTF / 128, NB), 256, 0, stream>>>(
      xt, wlt, origin, bl);
  // g2 = h @ W2  (overwrites xt slot — xt dead after gemm_o)
  gemm_f32<false><<<dim3(NN / 128, OUTF / 128, NB), 256, 0, stream>>>(
      hb, w2t, g2, nullptr);
  // out = (Agg(g2)+b2) * origin, transposed to [B][OUT][N]
  stencil2<<<dim3(256, NB), 256, 0, stream>>>(g2, origin, b2, out);
}